// Round 2
// baseline (357.302 us; speedup 1.0000x reference)
//
#include <hip/hip_runtime.h>

// Problem constants (B=4, C_IN=C_OUT=64, H=W=128, K=3, stride=1, pad=1)
// All I/O is fp32 (reference dtypes are float32).
#define HH   128
#define WWD  128
#define HW   16384      // H*W
#define NPX  65536      // B*H*W
#define CIN  64
#define COUT 64

// ---------------------------------------------------------------------------
// Kernel W-transpose: dcn_w[o][c][k] -> wt[k][c][o] in ws
// ---------------------------------------------------------------------------
__global__ void k_wt(const float* __restrict__ dw, float* __restrict__ wt) {
    int i = blockIdx.x * 256 + threadIdx.x;
    if (i < 9 * 64 * 64) {
        int k = i >> 12;
        int c = (i >> 6) & 63;
        int o = i & 63;
        wt[i] = dw[(((o << 6) | c) * 9) + k];
    }
}

// ---------------------------------------------------------------------------
// Kernel A: offset conv 64->18, 3x3, pad 1. One thread per pixel, 18 accs.
// Weights in LDS as [c][tap][m] padded to stride 20 (80B, 16B-aligned float4).
// Output fp32, plane-major offb[m][NPX].
// ---------------------------------------------------------------------------
__global__ __launch_bounds__(256)
void k_offset_conv(const float* __restrict__ x, const float* __restrict__ ow,
                   const float* __restrict__ ob, float* __restrict__ offb) {
    __shared__ __align__(16) float wl[11520];  // 64*9*20 floats = 46 KB
    int tid = threadIdx.x;
    for (int i = tid; i < 18 * 64 * 9; i += 256) {
        int m = i / 576;
        int r = i - m * 576;
        int c = r / 9;
        int tap = r - c * 9;
        wl[(c * 9 + tap) * 20 + m] = ow[i];
    }
    __syncthreads();

    int p  = blockIdx.x * 256 + tid;
    int b  = p >> 14;
    int hw = p & (HW - 1);
    int h  = hw >> 7;
    int w  = hw & (WWD - 1);

    float acc[18];
#pragma unroll
    for (int m = 0; m < 18; ++m) acc[m] = ob[m];

    const float* xb = x + b * CIN * HW;
#pragma unroll
    for (int tap = 0; tap < 9; ++tap) {
        int y  = h + tap / 3 - 1;
        int xx = w + tap % 3 - 1;
        if ((unsigned)y < (unsigned)HH && (unsigned)xx < (unsigned)WWD) {
            const float* xp = xb + y * WWD + xx;
#pragma unroll 8
            for (int c = 0; c < 64; ++c) {
                float xv = xp[c * HW];
                const float* wp = &wl[(c * 9 + tap) * 20];
#pragma unroll
                for (int m4 = 0; m4 < 4; ++m4) {
                    float4 wv = *(const float4*)(wp + m4 * 4);
                    acc[m4 * 4 + 0] = fmaf(xv, wv.x, acc[m4 * 4 + 0]);
                    acc[m4 * 4 + 1] = fmaf(xv, wv.y, acc[m4 * 4 + 1]);
                    acc[m4 * 4 + 2] = fmaf(xv, wv.z, acc[m4 * 4 + 2]);
                    acc[m4 * 4 + 3] = fmaf(xv, wv.w, acc[m4 * 4 + 3]);
                }
                acc[16] = fmaf(xv, wp[16], acc[16]);
                acc[17] = fmaf(xv, wp[17], acc[17]);
            }
        }
    }
#pragma unroll
    for (int m = 0; m < 18; ++m) offb[m * NPX + p] = acc[m];
}

// ---------------------------------------------------------------------------
// Kernel B: deformable sampling + main conv as K-chunked GEMM + BN partials.
// Block = 64 pixels x 64 out-channels, 256 threads.
// Per tap: stage S[c][px] (bilinear-sampled) and W[c][o] in LDS,
// then 4px x 4out register-blocked fp32 GEMM.
// ---------------------------------------------------------------------------
__global__ __launch_bounds__(256)
void k_dcn(const float* __restrict__ x, const float* __restrict__ offb,
           const float* __restrict__ wt, float* __restrict__ out,
           float* __restrict__ sums) {
    __shared__ __align__(16) float S[4096];    // S[c][px]
    __shared__ __align__(16) float Wl[4096];   // W[c][o] for current tap
    __shared__ float offs[18][64];

    int tid = threadIdx.x;
    int p0  = blockIdx.x * 64;
    int b   = p0 >> 14;
    int hw0 = p0 & (HW - 1);

    for (int i = tid; i < 18 * 64; i += 256)
        offs[i >> 6][i & 63] = offb[(i >> 6) * NPX + p0 + (i & 63)];

    int px = tid & 63;          // pixel lane for sampling phase
    int cg = tid >> 6;          // channel group (16 ch each)
    int hw = hw0 + px;
    int h  = hw >> 7;
    int w  = hw & (WWD - 1);
    const float* xb = x + b * CIN * HW;

    int pxb = (tid & 15) << 2;  // GEMM: 4-px group
    int obo = (tid >> 4) << 2;  // GEMM: 4-out group
    float acc[4][4] = {{0.f, 0.f, 0.f, 0.f}};

    for (int k = 0; k < 9; ++k) {
        __syncthreads();  // protect S/Wl reuse (also publishes offs on k=0)

        // stage this tap's weights [c][o], coalesced fp32
        for (int i = tid; i < 4096; i += 256)
            Wl[i] = wt[(k << 12) + i];

        // bilinear coordinates for this (px, tap) — reference semantics:
        // per-corner validity on float coords, clamp for the gather index
        float dy  = offs[2 * k][px];
        float dx  = offs[2 * k + 1][px];
        float py  = dy + (float)(h + k / 3 - 1);
        float pf  = dx + (float)(w + k % 3 - 1);
        float y0f = floorf(py);
        float x0f = floorf(pf);
        float wy  = py - y0f;
        float wx  = pf - x0f;
        int   iy0 = (int)y0f;
        int   ix0 = (int)x0f;
        float vy0 = (y0f >=  0.f && y0f <= 127.f) ? 1.f : 0.f;
        float vy1 = (y0f >= -1.f && y0f <= 126.f) ? 1.f : 0.f;
        float vx0 = (x0f >=  0.f && x0f <= 127.f) ? 1.f : 0.f;
        float vx1 = (x0f >= -1.f && x0f <= 126.f) ? 1.f : 0.f;
        int cy0 = min(max(iy0, 0), 127);
        int cy1 = min(max(iy0 + 1, 0), 127);
        int cx0 = min(max(ix0, 0), 127);
        int cx1 = min(max(ix0 + 1, 0), 127);
        float w00 = (1.f - wy) * (1.f - wx) * vy0 * vx0;
        float w01 = (1.f - wy) * wx * vy0 * vx1;
        float w10 = wy * (1.f - wx) * vy1 * vx0;
        float w11 = wy * wx * vy1 * vx1;
        int a00 = cy0 * WWD + cx0;
        int a01 = cy0 * WWD + cx1;
        int a10 = cy1 * WWD + cx0;
        int a11 = cy1 * WWD + cx1;

        const float* xc = xb + cg * 16 * HW;
#pragma unroll 4
        for (int cc = 0; cc < 16; ++cc) {
            float v = w00 * xc[a00] + w01 * xc[a01]
                    + w10 * xc[a10] + w11 * xc[a11];
            S[(cg * 16 + cc) * 64 + px] = v;
            xc += HW;
        }
        __syncthreads();

        // GEMM accumulate: acc[i][j] += S[c][pxb+i] * W[c][obo+j]
#pragma unroll 4
        for (int c = 0; c < 64; ++c) {
            float4 sv = *(const float4*)&S[(c << 6) + pxb];
            float4 wv = *(const float4*)&Wl[(c << 6) + obo];
            acc[0][0] = fmaf(sv.x, wv.x, acc[0][0]);
            acc[0][1] = fmaf(sv.x, wv.y, acc[0][1]);
            acc[0][2] = fmaf(sv.x, wv.z, acc[0][2]);
            acc[0][3] = fmaf(sv.x, wv.w, acc[0][3]);
            acc[1][0] = fmaf(sv.y, wv.x, acc[1][0]);
            acc[1][1] = fmaf(sv.y, wv.y, acc[1][1]);
            acc[1][2] = fmaf(sv.y, wv.z, acc[1][2]);
            acc[1][3] = fmaf(sv.y, wv.w, acc[1][3]);
            acc[2][0] = fmaf(sv.z, wv.x, acc[2][0]);
            acc[2][1] = fmaf(sv.z, wv.y, acc[2][1]);
            acc[2][2] = fmaf(sv.z, wv.z, acc[2][2]);
            acc[2][3] = fmaf(sv.z, wv.w, acc[2][3]);
            acc[3][0] = fmaf(sv.w, wv.x, acc[3][0]);
            acc[3][1] = fmaf(sv.w, wv.y, acc[3][1]);
            acc[3][2] = fmaf(sv.w, wv.z, acc[3][2]);
            acc[3][3] = fmaf(sv.w, wv.w, acc[3][3]);
        }
    }

    // epilogue: pre-BN fp32 to d_out (scratch), per-channel sum/sumsq partials
    int base = (((b << 6) + obo) * HW) + hw0 + pxb;
#pragma unroll
    for (int j = 0; j < 4; ++j) {
        float v0 = acc[0][j], v1 = acc[1][j], v2 = acc[2][j], v3 = acc[3][j];
        float4 sv = make_float4(v0, v1, v2, v3);
        *(float4*)&out[base + j * HW] = sv;

        float s = v0 + v1 + v2 + v3;
        float q = v0 * v0 + v1 * v1 + v2 * v2 + v3 * v3;
#pragma unroll
        for (int msk = 1; msk < 16; msk <<= 1) {
            s += __shfl_xor(s, msk);
            q += __shfl_xor(q, msk);
        }
        if ((tid & 15) == 0) {
            atomicAdd(&sums[obo + j], s);
            atomicAdd(&sums[64 + obo + j], q);
        }
    }
}

// ---------------------------------------------------------------------------
// Kernel C: BN (biased var) + gamma/beta + ReLU, in place over d_out.
// ---------------------------------------------------------------------------
__global__ __launch_bounds__(256)
void k_bn(float* __restrict__ out, const float* __restrict__ sums,
          const float* __restrict__ gamma, const float* __restrict__ beta) {
    int i4 = blockIdx.x * 256 + threadIdx.x;
    int e  = i4 << 2;
    int o  = (e >> 14) & 63;
    const float n = 65536.f;
    float mean = sums[o] / n;
    float var  = fmaxf(sums[64 + o] / n - mean * mean, 0.f);
    float sc   = rsqrtf(var + 1e-5f) * gamma[o];
    float sh   = beta[o] - mean * sc;
    float4 v = *(const float4*)&out[e];
    v.x = fmaxf(fmaf(v.x, sc, sh), 0.f);
    v.y = fmaxf(fmaf(v.y, sc, sh), 0.f);
    v.z = fmaxf(fmaf(v.z, sc, sh), 0.f);
    v.w = fmaxf(fmaf(v.w, sc, sh), 0.f);
    *(float4*)&out[e] = v;
}

// ---------------------------------------------------------------------------
// Workspace layout (fp32 elements):
//   offb : [0, 1179648)            18 * 65536 offsets, plane-major [m][px]
//   wt   : [1179648, 1216512)      9*64*64 transposed main-conv weights
//   sums : [1216512, 1216640)      64 sum + 64 sumsq (zeroed each call)
// Total 4.87 MB.
// ---------------------------------------------------------------------------
extern "C" void kernel_launch(void* const* d_in, const int* in_sizes, int n_in,
                              void* d_out, int out_size, void* d_ws, size_t ws_size,
                              hipStream_t stream) {
    const float* x     = (const float*)d_in[0];
    const float* ow    = (const float*)d_in[1];
    const float* ob    = (const float*)d_in[2];
    const float* dw    = (const float*)d_in[3];
    const float* gamma = (const float*)d_in[4];
    const float* beta  = (const float*)d_in[5];
    float* out  = (float*)d_out;
    float* ws   = (float*)d_ws;
    float* offb = ws;
    float* wt   = ws + 1179648;
    float* sums = ws + 1216512;

    hipMemsetAsync(sums, 0, 128 * sizeof(float), stream);
    k_wt<<<144, 256, 0, stream>>>(dw, wt);
    k_offset_conv<<<256, 256, 0, stream>>>(x, ow, ob, offb);
    k_dcn<<<1024, 256, 0, stream>>>(x, offb, wt, out, sums);
    k_bn<<<4096, 256, 0, stream>>>(out, sums, gamma, beta);
}

// Round 3
// 297.904 us; speedup vs baseline: 1.1994x; 1.1994x over previous
//
#include <hip/hip_runtime.h>

// Problem constants (B=4, C_IN=C_OUT=64, H=W=128, K=3, stride=1, pad=1)
// All I/O is fp32.
#define HH   128
#define WWD  128
#define HW   16384      // H*W
#define NPX  65536      // B*H*W
#define CIN  64
#define COUT 64

// XCD-contiguity swizzle for 1024-block grids: round-robin dispatch sends
// blockIdx%8 to XCD (heuristic); remap so each XCD owns a contiguous
// 128-block (8192-px) span -> co-resident L2 footprint ~2.3MB < 4MB.
__device__ __forceinline__ int swizzle1024(int bid) {
    return (bid & 7) * 128 + (bid >> 3);
}

// ---------------------------------------------------------------------------
// Kernel W-transpose: dcn_w[o][c][k] -> wt[k][c][o] in ws
// ---------------------------------------------------------------------------
__global__ void k_wt(const float* __restrict__ dw, float* __restrict__ wt) {
    int i = blockIdx.x * 256 + threadIdx.x;
    if (i < 9 * 64 * 64) {
        int k = i >> 12;
        int c = (i >> 6) & 63;
        int o = i & 63;
        wt[i] = dw[(((o << 6) | c) * 9) + k];
    }
}

// ---------------------------------------------------------------------------
// Kernel A: offset conv 64->18, 3x3, pad 1.
// 1024 blocks x 256 threads: 64 px x 4 channel-quarters per block.
// Each thread accumulates 18 outputs over its 16 channels; LDS reduction
// combines the 4 partials. Weight reads are wave-uniform (LDS broadcast).
// Output fp32, plane-major offb[m][NPX].
// ---------------------------------------------------------------------------
__global__ __launch_bounds__(256)
void k_offset_conv(const float* __restrict__ x, const float* __restrict__ ow,
                   const float* __restrict__ ob, float* __restrict__ offb) {
    __shared__ __align__(16) float wl[11520];   // [c][tap][m] pad 20 — 46 KB
    __shared__ float red[4][18][64];            // 18 KB
    int tid = threadIdx.x;
    for (int i = tid; i < 18 * 64 * 9; i += 256) {
        int m = i / 576;
        int r = i - m * 576;
        int c = r / 9;
        int tap = r - c * 9;
        wl[(c * 9 + tap) * 20 + m] = ow[i];
    }

    int vb  = swizzle1024(blockIdx.x);
    int p0  = vb * 64;
    int b   = p0 >> 14;
    int hw0 = p0 & (HW - 1);
    int px  = tid & 63;
    int cq  = tid >> 6;
    int hw  = hw0 + px;
    int h   = hw >> 7;
    int w   = hw & (WWD - 1);

    float acc[18];
#pragma unroll
    for (int m = 0; m < 18; ++m) acc[m] = 0.f;

    const float* xb = x + b * CIN * HW + cq * 16 * HW;
    __syncthreads();

#pragma unroll
    for (int tap = 0; tap < 9; ++tap) {
        int y  = h + tap / 3 - 1;
        int xx = w + tap % 3 - 1;
        if ((unsigned)y < (unsigned)HH && (unsigned)xx < (unsigned)WWD) {
            const float* xp = xb + y * WWD + xx;
#pragma unroll 4
            for (int c16 = 0; c16 < 16; ++c16) {
                float xv = xp[c16 * HW];
                const float* wp = &wl[((cq * 16 + c16) * 9 + tap) * 20];
#pragma unroll
                for (int m4 = 0; m4 < 4; ++m4) {
                    float4 wv = *(const float4*)(wp + m4 * 4);
                    acc[m4 * 4 + 0] = fmaf(xv, wv.x, acc[m4 * 4 + 0]);
                    acc[m4 * 4 + 1] = fmaf(xv, wv.y, acc[m4 * 4 + 1]);
                    acc[m4 * 4 + 2] = fmaf(xv, wv.z, acc[m4 * 4 + 2]);
                    acc[m4 * 4 + 3] = fmaf(xv, wv.w, acc[m4 * 4 + 3]);
                }
                acc[16] = fmaf(xv, wp[16], acc[16]);
                acc[17] = fmaf(xv, wp[17], acc[17]);
            }
        }
    }

#pragma unroll
    for (int m = 0; m < 18; ++m) red[cq][m][px] = acc[m];
    __syncthreads();
    for (int i = tid; i < 1152; i += 256) {
        int m = i >> 6;
        int p = i & 63;
        float v = red[0][m][p] + red[1][m][p] + red[2][m][p] + red[3][m][p]
                + ob[m];
        offb[m * NPX + p0 + p] = v;
    }
}

// ---------------------------------------------------------------------------
// Kernel B: deformable sampling + main conv as K-chunked GEMM + BN partials.
// Block = 64 pixels x 64 out-channels, 256 threads, XCD-swizzled.
// Per tap: stage S[c][px] (bilinear-sampled) and W[c][o] in LDS,
// then 4px x 4out register-blocked fp32 GEMM.
// ---------------------------------------------------------------------------
__global__ __launch_bounds__(256)
void k_dcn(const float* __restrict__ x, const float* __restrict__ offb,
           const float* __restrict__ wt, float* __restrict__ out,
           float* __restrict__ sums) {
    __shared__ __align__(16) float S[4096];    // S[c][px]
    __shared__ __align__(16) float Wl[4096];   // W[c][o] for current tap
    __shared__ float offs[18][64];

    int tid = threadIdx.x;
    int vb  = swizzle1024(blockIdx.x);
    int p0  = vb * 64;
    int b   = p0 >> 14;
    int hw0 = p0 & (HW - 1);

    for (int i = tid; i < 18 * 64; i += 256)
        offs[i >> 6][i & 63] = offb[(i >> 6) * NPX + p0 + (i & 63)];

    int px = tid & 63;          // pixel lane for sampling phase
    int cg = tid >> 6;          // channel group (16 ch each)
    int hw = hw0 + px;
    int h  = hw >> 7;
    int w  = hw & (WWD - 1);
    const float* xb = x + b * CIN * HW;

    int pxb = (tid & 15) << 2;  // GEMM: 4-px group
    int obo = (tid >> 4) << 2;  // GEMM: 4-out group
    float acc[4][4] = {{0.f, 0.f, 0.f, 0.f}};

    for (int k = 0; k < 9; ++k) {
        __syncthreads();  // protect S/Wl reuse (also publishes offs on k=0)

        // stage this tap's weights [c][o], coalesced fp32
        for (int i = tid; i < 4096; i += 256)
            Wl[i] = wt[(k << 12) + i];

        // bilinear coordinates — reference semantics: per-corner validity on
        // float coords, clamp for the gather index
        float dy  = offs[2 * k][px];
        float dx  = offs[2 * k + 1][px];
        float py  = dy + (float)(h + k / 3 - 1);
        float pf  = dx + (float)(w + k % 3 - 1);
        float y0f = floorf(py);
        float x0f = floorf(pf);
        float wy  = py - y0f;
        float wx  = pf - x0f;
        int   iy0 = (int)y0f;
        int   ix0 = (int)x0f;
        float vy0 = (y0f >=  0.f && y0f <= 127.f) ? 1.f : 0.f;
        float vy1 = (y0f >= -1.f && y0f <= 126.f) ? 1.f : 0.f;
        float vx0 = (x0f >=  0.f && x0f <= 127.f) ? 1.f : 0.f;
        float vx1 = (x0f >= -1.f && x0f <= 126.f) ? 1.f : 0.f;
        int cy0 = min(max(iy0, 0), 127);
        int cy1 = min(max(iy0 + 1, 0), 127);
        int cx0 = min(max(ix0, 0), 127);
        int cx1 = min(max(ix0 + 1, 0), 127);
        float w00 = (1.f - wy) * (1.f - wx) * vy0 * vx0;
        float w01 = (1.f - wy) * wx * vy0 * vx1;
        float w10 = wy * (1.f - wx) * vy1 * vx0;
        float w11 = wy * wx * vy1 * vx1;
        int a00 = cy0 * WWD + cx0;
        int a01 = cy0 * WWD + cx1;
        int a10 = cy1 * WWD + cx0;
        int a11 = cy1 * WWD + cx1;

        const float* xc = xb + cg * 16 * HW;
#pragma unroll 4
        for (int cc = 0; cc < 16; ++cc) {
            float v = w00 * xc[a00] + w01 * xc[a01]
                    + w10 * xc[a10] + w11 * xc[a11];
            S[(cg * 16 + cc) * 64 + px] = v;
            xc += HW;
        }
        __syncthreads();

        // GEMM accumulate: acc[i][j] += S[c][pxb+i] * W[c][obo+j]
#pragma unroll 4
        for (int c = 0; c < 64; ++c) {
            float4 sv = *(const float4*)&S[(c << 6) + pxb];
            float4 wv = *(const float4*)&Wl[(c << 6) + obo];
            acc[0][0] = fmaf(sv.x, wv.x, acc[0][0]);
            acc[0][1] = fmaf(sv.x, wv.y, acc[0][1]);
            acc[0][2] = fmaf(sv.x, wv.z, acc[0][2]);
            acc[0][3] = fmaf(sv.x, wv.w, acc[0][3]);
            acc[1][0] = fmaf(sv.y, wv.x, acc[1][0]);
            acc[1][1] = fmaf(sv.y, wv.y, acc[1][1]);
            acc[1][2] = fmaf(sv.y, wv.z, acc[1][2]);
            acc[1][3] = fmaf(sv.y, wv.w, acc[1][3]);
            acc[2][0] = fmaf(sv.z, wv.x, acc[2][0]);
            acc[2][1] = fmaf(sv.z, wv.y, acc[2][1]);
            acc[2][2] = fmaf(sv.z, wv.z, acc[2][2]);
            acc[2][3] = fmaf(sv.z, wv.w, acc[2][3]);
            acc[3][0] = fmaf(sv.w, wv.x, acc[3][0]);
            acc[3][1] = fmaf(sv.w, wv.y, acc[3][1]);
            acc[3][2] = fmaf(sv.w, wv.z, acc[3][2]);
            acc[3][3] = fmaf(sv.w, wv.w, acc[3][3]);
        }
    }

    // epilogue: pre-BN fp32 to d_out (scratch), per-channel sum/sumsq partials
    int base = (((b << 6) + obo) * HW) + hw0 + pxb;
#pragma unroll
    for (int j = 0; j < 4; ++j) {
        float v0 = acc[0][j], v1 = acc[1][j], v2 = acc[2][j], v3 = acc[3][j];
        float4 sv = make_float4(v0, v1, v2, v3);
        *(float4*)&out[base + j * HW] = sv;

        float s = v0 + v1 + v2 + v3;
        float q = v0 * v0 + v1 * v1 + v2 * v2 + v3 * v3;
#pragma unroll
        for (int msk = 1; msk < 16; msk <<= 1) {
            s += __shfl_xor(s, msk);
            q += __shfl_xor(q, msk);
        }
        if ((tid & 15) == 0) {
            atomicAdd(&sums[obo + j], s);
            atomicAdd(&sums[64 + obo + j], q);
        }
    }
}

// ---------------------------------------------------------------------------
// Kernel C: BN (biased var) + gamma/beta + ReLU, in place over d_out.
// ---------------------------------------------------------------------------
__global__ __launch_bounds__(256)
void k_bn(float* __restrict__ out, const float* __restrict__ sums,
          const float* __restrict__ gamma, const float* __restrict__ beta) {
    int i4 = blockIdx.x * 256 + threadIdx.x;
    int e  = i4 << 2;
    int o  = (e >> 14) & 63;
    const float n = 65536.f;
    float mean = sums[o] / n;
    float var  = fmaxf(sums[64 + o] / n - mean * mean, 0.f);
    float sc   = rsqrtf(var + 1e-5f) * gamma[o];
    float sh   = beta[o] - mean * sc;
    float4 v = *(const float4*)&out[e];
    v.x = fmaxf(fmaf(v.x, sc, sh), 0.f);
    v.y = fmaxf(fmaf(v.y, sc, sh), 0.f);
    v.z = fmaxf(fmaf(v.z, sc, sh), 0.f);
    v.w = fmaxf(fmaf(v.w, sc, sh), 0.f);
    *(float4*)&out[e] = v;
}

// ---------------------------------------------------------------------------
// Workspace layout (fp32 elements):
//   offb : [0, 1179648)            18 * 65536 offsets, plane-major [m][px]
//   wt   : [1179648, 1216512)      9*64*64 transposed main-conv weights
//   sums : [1216512, 1216640)      64 sum + 64 sumsq (zeroed each call)
// ---------------------------------------------------------------------------
extern "C" void kernel_launch(void* const* d_in, const int* in_sizes, int n_in,
                              void* d_out, int out_size, void* d_ws, size_t ws_size,
                              hipStream_t stream) {
    const float* x     = (const float*)d_in[0];
    const float* ow    = (const float*)d_in[1];
    const float* ob    = (const float*)d_in[2];
    const float* dw    = (const float*)d_in[3];
    const float* gamma = (const float*)d_in[4];
    const float* beta  = (const float*)d_in[5];
    float* out  = (float*)d_out;
    float* ws   = (float*)d_ws;
    float* offb = ws;
    float* wt   = ws + 1179648;
    float* sums = ws + 1216512;

    hipMemsetAsync(sums, 0, 128 * sizeof(float), stream);
    k_wt<<<144, 256, 0, stream>>>(dw, wt);
    k_offset_conv<<<1024, 256, 0, stream>>>(x, ow, ob, offb);
    k_dcn<<<1024, 256, 0, stream>>>(x, offb, wt, out, sums);
    k_bn<<<4096, 256, 0, stream>>>(out, sums, gamma, beta);
}

// Round 4
// 156.060 us; speedup vs baseline: 2.2895x; 1.9089x over previous
//
#include <hip/hip_runtime.h>

// Problem constants (B=4, C_IN=C_OUT=64, H=W=128, K=3, stride=1, pad=1)
// Harness I/O is fp32. Internally: NHWC bf16 x + bf16 MFMA GEMMs.
#define HW   16384      // H*W
#define NPX  65536      // B*H*W

typedef unsigned short u16;
typedef unsigned int   u32;
typedef short bf16x8 __attribute__((ext_vector_type(8)));   // 8 bf16 = 4 VGPR
typedef float f32x4  __attribute__((ext_vector_type(4)));   // MFMA acc

__device__ __forceinline__ u16 f2b(float f) {               // fp32->bf16 RNE
    u32 u = __float_as_uint(f);
    return (u16)((u + 0x7FFFu + ((u >> 16) & 1u)) >> 16);
}
__device__ __forceinline__ float blo(u32 u) { return __uint_as_float(u << 16); }
__device__ __forceinline__ float bhi(u32 u) { return __uint_as_float(u & 0xffff0000u); }

// XCD-contiguity swizzle (1024-block grids): each XCD gets a contiguous span.
__device__ __forceinline__ int swizzle1024(int bid) {
    return (bid & 7) * 128 + (bid >> 3);
}

// bilinear blend of one u32 (2 bf16 channels) x 4 corners -> packed bf16 pair
__device__ __forceinline__ u32 comb(u32 a00, u32 a01, u32 a10, u32 a11,
                                    float w00, float w01, float w10, float w11) {
    float lo = fmaf(w11, blo(a11), fmaf(w10, blo(a10), fmaf(w01, blo(a01), w00 * blo(a00))));
    float hi = fmaf(w11, bhi(a11), fmaf(w10, bhi(a10), fmaf(w01, bhi(a01), w00 * bhi(a00))));
    return ((__float_as_uint(lo) + 0x8000u) >> 16) | ((__float_as_uint(hi) + 0x8000u) & 0xffff0000u);
}

// ---------------------------------------------------------------------------
// k_pre: x NCHW fp32 -> xh NHWC bf16.  Block = 64 px tile, LDS transpose.
// ---------------------------------------------------------------------------
__global__ __launch_bounds__(256)
void k_pre(const float* __restrict__ x, u16* __restrict__ xh) {
    __shared__ float tile[64][65];
    int tid = threadIdx.x;
    int p0  = blockIdx.x * 64;
    int b   = p0 >> 14;
    int hw0 = p0 & (HW - 1);

    int c  = tid >> 2;
    int ch = (tid & 3) * 16;
    const float* src = x + (b * 64 + c) * HW + hw0 + ch;
#pragma unroll
    for (int i = 0; i < 4; ++i) {
        float4 v = *(const float4*)(src + i * 4);
        tile[c][ch + i * 4 + 0] = v.x;
        tile[c][ch + i * 4 + 1] = v.y;
        tile[c][ch + i * 4 + 2] = v.z;
        tile[c][ch + i * 4 + 3] = v.w;
    }
    __syncthreads();

    int px = tid >> 2;
    int cc = (tid & 3) * 16;
    u32 w[8];
#pragma unroll
    for (int i = 0; i < 8; ++i) {
        u32 lo = f2b(tile[cc + 2 * i][px]);
        u32 hi = f2b(tile[cc + 2 * i + 1][px]);
        w[i] = lo | (hi << 16);
    }
    u16* dst = xh + (size_t)(p0 + px) * 64 + cc;
    *(int4*)dst       = make_int4(w[0], w[1], w[2], w[3]);
    *(int4*)(dst + 8) = make_int4(w[4], w[5], w[6], w[7]);
}

// ---------------------------------------------------------------------------
// k_wt: pre-arrange weights into B-fragment-linear bf16.
//   B-frag (16x16x32): lane holds B[k = (lane>>4)*8 + j][n = lane&15], j=0..7.
//   wtd: dcn_w, fid = tap*8 + kstep*4 + ntile  (72 frags, N=64)
//   wto: offset_w, fid = tap*4 + kstep*2 + ntile (36 frags, N=32, n>=18 -> 0)
// ---------------------------------------------------------------------------
__global__ void k_wt(const float* __restrict__ dw, const float* __restrict__ ow,
                     u16* __restrict__ wtd, u16* __restrict__ wto) {
    int gid = blockIdx.x * 256 + threadIdx.x;
    if (gid >= 108 * 64) return;
    int fid = gid >> 6, lane = gid & 63;
    int mi = lane & 15, quad = lane >> 4;
    u32 w[4];
    if (fid < 72) {
        int tap = fid >> 3, rem = fid & 7;
        int ks = rem >> 2, nt = rem & 3;
        int n = nt * 16 + mi;
        int cb = ks * 32 + quad * 8;
#pragma unroll
        for (int i = 0; i < 4; ++i) {
            u32 lo = f2b(dw[(n * 64 + cb + 2 * i) * 9 + tap]);
            u32 hi = f2b(dw[(n * 64 + cb + 2 * i + 1) * 9 + tap]);
            w[i] = lo | (hi << 16);
        }
        *((int4*)wtd + (fid << 6) + lane) = make_int4(w[0], w[1], w[2], w[3]);
    } else {
        int f2 = fid - 72;
        int tap = f2 >> 2, rem = f2 & 3;
        int ks = rem >> 1, nt = rem & 1;
        int n = nt * 16 + mi;
        int cb = ks * 32 + quad * 8;
#pragma unroll
        for (int i = 0; i < 4; ++i) {
            u32 lo = (n < 18) ? f2b(ow[(n * 64 + cb + 2 * i) * 9 + tap]) : 0u;
            u32 hi = (n < 18) ? f2b(ow[(n * 64 + cb + 2 * i + 1) * 9 + tap]) : 0u;
            w[i] = lo | (hi << 16);
        }
        *((int4*)wto + (f2 << 6) + lane) = make_int4(w[0], w[1], w[2], w[3]);
    }
}

// ---------------------------------------------------------------------------
// k_offset: offset conv as MFMA GEMM.  Block = 64 px (one row segment),
// wave = 16 px x 32 n (18 used).  A-frags direct from global NHWC bf16,
// boundary handled by clamp+select.  No LDS, no barriers.
// ---------------------------------------------------------------------------
__global__ __launch_bounds__(256)
void k_offset(const u16* __restrict__ xh, const u16* __restrict__ wto,
              const float* __restrict__ ob, float* __restrict__ offb) {
    int tid = threadIdx.x;
    int vb  = swizzle1024(blockIdx.x);
    int p0  = vb * 64;
    int b   = p0 >> 14;
    int hw0 = p0 & (HW - 1);
    int y   = hw0 >> 7;
    int x0  = hw0 & 127;
    int wave = tid >> 6, lane = tid & 63;
    int mi = lane & 15, quad = lane >> 4;
    int m0 = wave << 4;
    int xcol = x0 + m0 + mi;

    f32x4 acc[2] = {{0.f, 0.f, 0.f, 0.f}, {0.f, 0.f, 0.f, 0.f}};
    const u16* xb = xh + (size_t)b * HW * 64;

#pragma unroll
    for (int tap = 0; tap < 9; ++tap) {
        int yy = y + tap / 3 - 1;
        if ((unsigned)yy < 128u) {
            int xx = xcol + tap % 3 - 1;
            bool xv = (unsigned)xx < 128u;
            int xc = min(max(xx, 0), 127);
            const u16* ap = xb + ((yy << 7) + xc) * 64;
#pragma unroll
            for (int ks = 0; ks < 2; ++ks) {
                int4 av = *(const int4*)(ap + ks * 32 + quad * 8);
                if (!xv) av = make_int4(0, 0, 0, 0);
                bf16x8 a = __builtin_bit_cast(bf16x8, av);
#pragma unroll
                for (int nt = 0; nt < 2; ++nt) {
                    bf16x8 bf = *((const bf16x8*)wto + ((tap * 4 + ks * 2 + nt) << 6) + lane);
                    acc[nt] = __builtin_amdgcn_mfma_f32_16x16x32_bf16(a, bf, acc[nt], 0, 0, 0);
                }
            }
        }
    }
    // C layout: col = lane&15 = n, row = quad*4 + reg = px-in-tile
#pragma unroll
    for (int nt = 0; nt < 2; ++nt) {
        int n = nt * 16 + mi;
        if (n < 18) {
            float bias = ob[n];
#pragma unroll
            for (int r = 0; r < 4; ++r)
                offb[n * NPX + p0 + m0 + quad * 4 + r] = acc[nt][r] + bias;
        }
    }
}

// ---------------------------------------------------------------------------
// k_dcn: deformable sample + main conv, MFMA.  Block = 64 px, wave = 16 px x
// 64 out.  Lane (quad = k-chunk, mi = px) gathers its own 8 channels' 4
// corners -> fp32 blend -> bf16 A-frag IN REGISTERS.  No barriers in K-loop.
// Epilogue: LDS transpose -> coalesced stores + BN sum/sumsq atomics.
// ---------------------------------------------------------------------------
__global__ __launch_bounds__(256)
void k_dcn(const u16* __restrict__ xh, const float* __restrict__ offb,
           const u16* __restrict__ wtd, float* __restrict__ out,
           float* __restrict__ sums) {
    __shared__ float so[64][65];
    int tid = threadIdx.x;
    int vb  = swizzle1024(blockIdx.x);
    int p0  = vb * 64;
    int b   = p0 >> 14;
    int hw0 = p0 & (HW - 1);
    int y   = hw0 >> 7;
    int x0  = hw0 & 127;
    int wave = tid >> 6, lane = tid & 63;
    int mi = lane & 15, quad = lane >> 4;
    int m0 = wave << 4;
    int pxg  = p0 + m0 + mi;
    int xcol = x0 + m0 + mi;

    float offv[18];
#pragma unroll
    for (int m = 0; m < 18; ++m) offv[m] = offb[m * NPX + pxg];

    f32x4 acc[4] = {{0.f,0.f,0.f,0.f},{0.f,0.f,0.f,0.f},{0.f,0.f,0.f,0.f},{0.f,0.f,0.f,0.f}};
    const u16* xb = xh + (size_t)b * HW * 64;

#pragma unroll
    for (int tap = 0; tap < 9; ++tap) {
        // reference semantics: per-corner float-coord validity, clamped gather
        float py  = offv[2 * tap]     + (float)(y    + tap / 3 - 1);
        float pf  = offv[2 * tap + 1] + (float)(xcol + tap % 3 - 1);
        float y0f = floorf(py);
        float x0f = floorf(pf);
        float wy  = py - y0f;
        float wx  = pf - x0f;
        int   iy0 = (int)y0f;
        int   ix0 = (int)x0f;
        float vy0 = (y0f >=  0.f && y0f <= 127.f) ? 1.f : 0.f;
        float vy1 = (y0f >= -1.f && y0f <= 126.f) ? 1.f : 0.f;
        float vx0 = (x0f >=  0.f && x0f <= 127.f) ? 1.f : 0.f;
        float vx1 = (x0f >= -1.f && x0f <= 126.f) ? 1.f : 0.f;
        int cy0 = min(max(iy0, 0), 127);
        int cy1 = min(max(iy0 + 1, 0), 127);
        int cx0 = min(max(ix0, 0), 127);
        int cx1 = min(max(ix0 + 1, 0), 127);
        float w00 = (1.f - wy) * (1.f - wx) * vy0 * vx0;
        float w01 = (1.f - wy) * wx * vy0 * vx1;
        float w10 = wy * (1.f - wx) * vy1 * vx0;
        float w11 = wy * wx * vy1 * vx1;
        const u16* p00 = xb + ((cy0 << 7) + cx0) * 64;
        const u16* p01 = xb + ((cy0 << 7) + cx1) * 64;
        const u16* p10 = xb + ((cy1 << 7) + cx0) * 64;
        const u16* p11 = xb + ((cy1 << 7) + cx1) * 64;

#pragma unroll
        for (int ks = 0; ks < 2; ++ks) {
            int koff = ks * 32 + quad * 8;
            int4 v00 = *(const int4*)(p00 + koff);
            int4 v01 = *(const int4*)(p01 + koff);
            int4 v10 = *(const int4*)(p10 + koff);
            int4 v11 = *(const int4*)(p11 + koff);
            int4 apk;
            apk.x = comb(v00.x, v01.x, v10.x, v11.x, w00, w01, w10, w11);
            apk.y = comb(v00.y, v01.y, v10.y, v11.y, w00, w01, w10, w11);
            apk.z = comb(v00.z, v01.z, v10.z, v11.z, w00, w01, w10, w11);
            apk.w = comb(v00.w, v01.w, v10.w, v11.w, w00, w01, w10, w11);
            bf16x8 a = __builtin_bit_cast(bf16x8, apk);
#pragma unroll
            for (int nt = 0; nt < 4; ++nt) {
                bf16x8 bf = *((const bf16x8*)wtd + ((tap * 8 + ks * 4 + nt) << 6) + lane);
                acc[nt] = __builtin_amdgcn_mfma_f32_16x16x32_bf16(a, bf, acc[nt], 0, 0, 0);
            }
        }
    }

    // epilogue: C layout col = lane&15 = n, row = quad*4+r = px-in-tile
#pragma unroll
    for (int nt = 0; nt < 4; ++nt)
#pragma unroll
        for (int r = 0; r < 4; ++r)
            so[nt * 16 + mi][m0 + quad * 4 + r] = acc[nt][r];
    __syncthreads();

    int n  = tid >> 2;
    int c4 = tid & 3;
    int pl = c4 * 16;
    float s = 0.f, q = 0.f;
    float vals[16];
#pragma unroll
    for (int i = 0; i < 16; ++i) {
        float v = so[n][pl + i];
        vals[i] = v;
        s += v;
        q = fmaf(v, v, q);
    }
    float* dst = out + ((b * 64 + n) * HW) + (y << 7) + x0 + pl;
#pragma unroll
    for (int i = 0; i < 4; ++i)
        *(float4*)(dst + i * 4) = make_float4(vals[4*i], vals[4*i+1], vals[4*i+2], vals[4*i+3]);

    s += __shfl_xor(s, 1); s += __shfl_xor(s, 2);
    q += __shfl_xor(q, 1); q += __shfl_xor(q, 2);
    if (c4 == 0) {
        atomicAdd(&sums[n], s);
        atomicAdd(&sums[64 + n], q);
    }
}

// ---------------------------------------------------------------------------
// k_bn: BN (biased var) + gamma/beta + ReLU, in place over d_out.
// ---------------------------------------------------------------------------
__global__ __launch_bounds__(256)
void k_bn(float* __restrict__ out, const float* __restrict__ sums,
          const float* __restrict__ gamma, const float* __restrict__ beta) {
    int i4 = blockIdx.x * 256 + threadIdx.x;
    int e  = i4 << 2;
    int o  = (e >> 14) & 63;
    const float n = 65536.f;
    float mean = sums[o] / n;
    float var  = fmaxf(sums[64 + o] / n - mean * mean, 0.f);
    float sc   = rsqrtf(var + 1e-5f) * gamma[o];
    float sh   = beta[o] - mean * sc;
    float4 v = *(const float4*)&out[e];
    v.x = fmaxf(fmaf(v.x, sc, sh), 0.f);
    v.y = fmaxf(fmaf(v.y, sc, sh), 0.f);
    v.z = fmaxf(fmaf(v.z, sc, sh), 0.f);
    v.w = fmaxf(fmaf(v.w, sc, sh), 0.f);
    *(float4*)&out[e] = v;
}

// ---------------------------------------------------------------------------
// Workspace layout (float units):
//   offb : [0, 1179648)          18 x 65536 fp32 offset planes
//   xh   : [1179648, 3276800)    NHWC bf16 x (4.19M u16)
//   wtd  : [3276800, 3295232)    72 B-frags dcn weights (bf16)
//   wto  : [3295232, 3304448)    36 B-frags offset weights (bf16)
//   sums : [3304448, 3304576)    BN partials (zeroed per call)
// Total ~13.2 MB.
// ---------------------------------------------------------------------------
extern "C" void kernel_launch(void* const* d_in, const int* in_sizes, int n_in,
                              void* d_out, int out_size, void* d_ws, size_t ws_size,
                              hipStream_t stream) {
    const float* x     = (const float*)d_in[0];
    const float* ow    = (const float*)d_in[1];
    const float* ob    = (const float*)d_in[2];
    const float* dw    = (const float*)d_in[3];
    const float* gamma = (const float*)d_in[4];
    const float* beta  = (const float*)d_in[5];
    float* out  = (float*)d_out;
    float* ws   = (float*)d_ws;
    float* offb = ws;
    u16*   xh   = (u16*)(ws + 1179648);
    u16*   wtd  = (u16*)(ws + 3276800);
    u16*   wto  = (u16*)(ws + 3295232);
    float* sums = ws + 3304448;

    hipMemsetAsync(sums, 0, 128 * sizeof(float), stream);
    k_pre<<<1024, 256, 0, stream>>>(x, xh);
    k_wt<<<27, 256, 0, stream>>>(dw, ow, wtd, wto);
    k_offset<<<1024, 256, 0, stream>>>(xh, wto, ob, offb);
    k_dcn<<<1024, 256, 0, stream>>>(xh, offb, wtd, out, sums);
    k_bn<<<4096, 256, 0, stream>>>(out, sums, gamma, beta);
}